// Round 3
// baseline (424.348 us; speedup 1.0000x reference)
//
#include <hip/hip_runtime.h>

// ExplicitLiePE: y[b,s] = expm(A) @ x[b,s],  A = sum_k r[b,s,k] * 0.5*(L_k - L_k^T)
// (P_sp = identity in this config).
//
// One wave per token; lane i holds row i of 2*A/rho in 64 VGPRs.
// exp(A)x via Jacobi-Anger/Chebyshev + Clenshaw, Bessel coefficients by
// Miller backward recurrence fused into the Clenshaw loop (verified R2).
//
// R3 changes vs R2:
//  - __launch_bounds__(512,4): VGPR <= 128 (R2 spiked to 208 -> 10% occupancy).
//  - TPB=512 / 8 tokens per block: 2 blocks/CU * 8 waves = 16 waves/CU.
//  - matvec broadcast via wave-private LDS buffer (1 ds_write_b32 + 16
//    ds_read_b128 broadcast) instead of 64 v_readlane: ~150 vs ~256 issue cyc.
//  - rho = 16.4*sigma + 1.5, M = floor(rho)+12 (was 17.3s+2, +14): ~12% fewer
//    matvecs; worst-case spectral edge 16*sigma still covered with margin.

#define TPB 512
#define TOKENS_PER_BLOCK 8
#define LPAD 68                  // float stride: rows 16B-aligned for ds_read_b128;
                                 // b128 row reads hit the structural minimum of
                                 // 8 words/bank (R1 measured 0 conflicts);
                                 // column reads are lane-consecutive (free)
#define LSTRIDE (64 * LPAD)

__device__ __forceinline__ float matvec_row(const float (&row)[64],
                                            const float* __restrict__ tb)
{
    float a0 = 0.f, a1 = 0.f, a2 = 0.f, a3 = 0.f;
    #pragma unroll
    for (int j4 = 0; j4 < 16; ++j4) {
        float4 t4 = *(const float4*)(tb + 4 * j4);   // same addr all lanes -> broadcast
        a0 = fmaf(row[4 * j4 + 0], t4.x, a0);
        a1 = fmaf(row[4 * j4 + 1], t4.y, a1);
        a2 = fmaf(row[4 * j4 + 2], t4.z, a2);
        a3 = fmaf(row[4 * j4 + 3], t4.w, a3);
    }
    return (a0 + a1) + (a2 + a3);
}

__global__ __launch_bounds__(TPB, 4) void liepe_kernel(
    const float* __restrict__ x,
    const float* __restrict__ r_grid,
    const float* __restrict__ L_param,
    float* __restrict__ out,
    int n_tokens)
{
    __shared__ __align__(16) float Lsh[3 * LSTRIDE];
    __shared__ __align__(16) float tbuf[TOKENS_PER_BLOCK][64];

    // Stage raw L (3x64x64) into LDS, padded stride. Coalesced global reads.
    for (int idx = threadIdx.x; idx < 3 * 64 * 64; idx += TPB) {
        int k = idx >> 12;
        int rem = idx & 4095;
        int i = rem >> 6;
        int j = rem & 63;
        Lsh[k * LSTRIDE + i * LPAD + j] = L_param[idx];
    }
    __syncthreads();

    const int lane = threadIdx.x & 63;
    const int wid  = threadIdx.x >> 6;
    const int bs   = blockIdx.x * TOKENS_PER_BLOCK + wid;
    if (bs >= n_tokens) return;

    float* tb = &tbuf[wid][0];

    const float r0 = r_grid[bs * 3 + 0];
    const float r1 = r_grid[bs * 3 + 1];
    const float r2 = r_grid[bs * 3 + 2];

    const float sig2 = 0.5f * (r0 * r0 + r1 * r1 + r2 * r2);
    const float rho  = fmaf(16.4f, __builtin_sqrtf(sig2), 1.5f);
    const float inv_rho = 1.0f / rho;
    const int M = (int)rho + 12;

    // rows hold 2*A/rho: coefficient per generator = r_k / rho
    const float c0 = r0 * inv_rho;
    const float c1 = r1 * inv_rho;
    const float c2 = r2 * inv_rho;

    // Build row[j] = (2A/rho)[lane][j] = sum_k c_k * (L_k[lane][j] - L_k[j][lane])
    float row[64];
    #pragma unroll
    for (int j4 = 0; j4 < 64; j4 += 4) {
        float acc0 = 0.f, acc1 = 0.f, acc2 = 0.f, acc3 = 0.f;
        #pragma unroll
        for (int k = 0; k < 3; ++k) {
            const float ck = (k == 0) ? c0 : ((k == 1) ? c1 : c2);
            const float* base = &Lsh[k * LSTRIDE];
            float4 a = *(const float4*)(base + lane * LPAD + j4);
            float b0v = base[(j4 + 0) * LPAD + lane];
            float b1v = base[(j4 + 1) * LPAD + lane];
            float b2v = base[(j4 + 2) * LPAD + lane];
            float b3v = base[(j4 + 3) * LPAD + lane];
            acc0 = fmaf(ck, a.x - b0v, acc0);
            acc1 = fmaf(ck, a.y - b1v, acc1);
            acc2 = fmaf(ck, a.z - b2v, acc2);
            acc3 = fmaf(ck, a.w - b3v, acc3);
        }
        row[j4 + 0] = acc0;
        row[j4 + 1] = acc1;
        row[j4 + 2] = acc2;
        row[j4 + 3] = acc3;
    }

    const float xv = x[bs * 64 + lane];

    // ---- Miller backward recurrence for unnormalized Jm(rho), fused Clenshaw ----
    float jp = 0.f;          // J~_{m+1}
    float jc = 1e-12f;       // J~_{m}, starting at m = ms
    const int ms = M + 10;
    float N = ((ms & 1) == 0) ? (jc + jc) : 0.f;   // normalizer: J0 + 2*sum_even Jm

    for (int m = ms; m > M; --m) {
        float jm = fmaf((2.f * (float)m) * inv_rho, jc, -jp);  // J~_{m-1}
        jp = jc; jc = jm;
        int mm = m - 1;
        if ((mm & 1) == 0) N += (mm > 0) ? (jm + jm) : jm;
    }
    // jc = J~_M.  b_M = a_M * x = 2*J~_M * x
    float b1 = (jc + jc) * xv;
    float b2 = 0.f;
    {   // advance to J~_{M-1}
        float jm = fmaf((2.f * (float)M) * inv_rho, jc, -jp);
        jp = jc; jc = jm;
        int mm = M - 1;
        if ((mm & 1) == 0) N += (mm > 0) ? (jm + jm) : jm;
    }

    // Clenshaw: b_m = 2*J~_m * x + (2A/rho) b_{m+1} + b_{m+2}
    #pragma unroll 1
    for (int m = M - 1; m >= 1; --m) {
        tb[lane] = b1;                       // ds_write_b32, conflict-free
        float t  = matvec_row(row, tb);      // (2A/rho) b1
        float bn = fmaf(jc + jc, xv, t + b2);
        b2 = b1; b1 = bn;
        float jm = fmaf((2.f * (float)m) * inv_rho, jc, -jp);
        jp = jc; jc = jm;
        int mm = m - 1;
        if ((mm & 1) == 0) N += (mm > 0) ? (jm + jm) : jm;
    }
    // jc = J~_0 (already folded into N). Final: b0 = J~_0 x + (2A/rho)b1 + b2;
    // result = (b0 - (A/rho) b1) / N  -- reuse t = (2A/rho) b1. (verified in R2)
    {
        tb[lane] = b1;
        float t  = matvec_row(row, tb);
        float b0 = fmaf(jc, xv, t + b2);
        float y  = (b0 - 0.5f * t) / N;
        out[bs * 64 + lane] = y;
    }
}

extern "C" void kernel_launch(void* const* d_in, const int* in_sizes, int n_in,
                              void* d_out, int out_size, void* d_ws, size_t ws_size,
                              hipStream_t stream) {
    const float* x = (const float*)d_in[0];
    const float* r = (const float*)d_in[1];
    const float* L = (const float*)d_in[2];
    // d_in[3] = P_sp: identity (allow_mixing=False) -> R_eff = R_r.
    float* out = (float*)d_out;

    int n_tokens = in_sizes[0] / 64;  // B*S = 8192
    int grid = (n_tokens + TOKENS_PER_BLOCK - 1) / TOKENS_PER_BLOCK;
    liepe_kernel<<<grid, TPB, 0, stream>>>(x, r, L, out, n_tokens);
}

// Round 4
// 255.263 us; speedup vs baseline: 1.6624x; 1.6624x over previous
//
#include <hip/hip_runtime.h>

// ExplicitLiePE: y[b,s] = expm(A) @ x[b,s],  A = sum_k r[b,s,k] * 0.5*(L_k - L_k^T)
// (P_sp = identity in this config).
//
// One wave per token; lane i holds row i of 2*A/rho in 64 VGPRs.
// exp(A)x via Jacobi-Anger/Chebyshev + Clenshaw; Bessel coefficients by Miller
// backward recurrence fused into the Clenshaw loop (math verified R2/R3).
//
// R4 changes vs R3 (which spilled row[64] to scratch -> 1.1 GB HBM traffic):
//  - TPB back to 256 (4 tokens/block), __launch_bounds__(256, 3): VGPR cap 168
//    >= the ~130 live set -> no spill; 3 blocks/CU via LDS 53,248 B -> 12 waves/CU.
//  - Keep the LDS-broadcast matvec from R3 (1 ds_write_b32 + 16 broadcast
//    ds_read_b128 on the LDS pipe instead of 64 v_readlane on the VALU pipe).

#define TPB 256
#define TOKENS_PER_BLOCK 4
#define LPAD 68                  // float stride: rows 16B-aligned for b128 LDS reads
                                 // (8 words/bank = wave64 structural minimum, R1
                                 // measured 0 conflicts); col reads lane-consecutive.
#define LSTRIDE (64 * LPAD)

__device__ __forceinline__ float matvec_row(const float (&row)[64],
                                            const float* tb)
{
    float a0 = 0.f, a1 = 0.f, a2 = 0.f, a3 = 0.f;
    #pragma unroll
    for (int j4 = 0; j4 < 16; ++j4) {
        float4 t4 = *(const float4*)(tb + 4 * j4);   // same addr all lanes -> broadcast
        a0 = fmaf(row[4 * j4 + 0], t4.x, a0);
        a1 = fmaf(row[4 * j4 + 1], t4.y, a1);
        a2 = fmaf(row[4 * j4 + 2], t4.z, a2);
        a3 = fmaf(row[4 * j4 + 3], t4.w, a3);
    }
    return (a0 + a1) + (a2 + a3);
}

__global__ __launch_bounds__(TPB, 3) void liepe_kernel(
    const float* __restrict__ x,
    const float* __restrict__ r_grid,
    const float* __restrict__ L_param,
    float* __restrict__ out,
    int n_tokens)
{
    __shared__ __align__(16) float Lsh[3 * LSTRIDE];
    __shared__ __align__(16) float tbuf[TOKENS_PER_BLOCK][64];

    // Stage raw L (3x64x64) into LDS, padded stride. Coalesced global reads.
    for (int idx = threadIdx.x; idx < 3 * 64 * 64; idx += TPB) {
        int k = idx >> 12;
        int rem = idx & 4095;
        int i = rem >> 6;
        int j = rem & 63;
        Lsh[k * LSTRIDE + i * LPAD + j] = L_param[idx];
    }
    __syncthreads();

    const int lane = threadIdx.x & 63;
    const int wid  = threadIdx.x >> 6;
    const int bs   = blockIdx.x * TOKENS_PER_BLOCK + wid;
    if (bs >= n_tokens) return;

    float* tb = &tbuf[wid][0];

    const float r0 = r_grid[bs * 3 + 0];
    const float r1 = r_grid[bs * 3 + 1];
    const float r2 = r_grid[bs * 3 + 2];

    const float sig2 = 0.5f * (r0 * r0 + r1 * r1 + r2 * r2);
    const float rho  = fmaf(16.4f, __builtin_sqrtf(sig2), 1.5f);
    const float inv_rho = 1.0f / rho;
    const int M = (int)rho + 12;

    // rows hold 2*A/rho: coefficient per generator = r_k / rho
    const float c0 = r0 * inv_rho;
    const float c1 = r1 * inv_rho;
    const float c2 = r2 * inv_rho;

    // Build row[j] = (2A/rho)[lane][j] = sum_k c_k * (L_k[lane][j] - L_k[j][lane])
    float row[64];
    #pragma unroll
    for (int j4 = 0; j4 < 64; j4 += 4) {
        float acc0 = 0.f, acc1 = 0.f, acc2 = 0.f, acc3 = 0.f;
        #pragma unroll
        for (int k = 0; k < 3; ++k) {
            const float ck = (k == 0) ? c0 : ((k == 1) ? c1 : c2);
            const float* base = &Lsh[k * LSTRIDE];
            float4 a = *(const float4*)(base + lane * LPAD + j4);
            float b0v = base[(j4 + 0) * LPAD + lane];
            float b1v = base[(j4 + 1) * LPAD + lane];
            float b2v = base[(j4 + 2) * LPAD + lane];
            float b3v = base[(j4 + 3) * LPAD + lane];
            acc0 = fmaf(ck, a.x - b0v, acc0);
            acc1 = fmaf(ck, a.y - b1v, acc1);
            acc2 = fmaf(ck, a.z - b2v, acc2);
            acc3 = fmaf(ck, a.w - b3v, acc3);
        }
        row[j4 + 0] = acc0;
        row[j4 + 1] = acc1;
        row[j4 + 2] = acc2;
        row[j4 + 3] = acc3;
    }

    const float xv = x[bs * 64 + lane];

    // ---- Miller backward recurrence for unnormalized Jm(rho), fused Clenshaw ----
    float jp = 0.f;          // J~_{m+1}
    float jc = 1e-12f;       // J~_{m}, starting at m = ms
    const int ms = M + 10;
    float N = ((ms & 1) == 0) ? (jc + jc) : 0.f;   // normalizer: J0 + 2*sum_even Jm

    for (int m = ms; m > M; --m) {
        float jm = fmaf((2.f * (float)m) * inv_rho, jc, -jp);  // J~_{m-1}
        jp = jc; jc = jm;
        int mm = m - 1;
        if ((mm & 1) == 0) N += (mm > 0) ? (jm + jm) : jm;
    }
    // jc = J~_M.  b_M = a_M * x = 2*J~_M * x
    float b1 = (jc + jc) * xv;
    float b2 = 0.f;
    {   // advance to J~_{M-1}
        float jm = fmaf((2.f * (float)M) * inv_rho, jc, -jp);
        jp = jc; jc = jm;
        int mm = M - 1;
        if ((mm & 1) == 0) N += (mm > 0) ? (jm + jm) : jm;
    }

    // Clenshaw: b_m = 2*J~_m * x + (2A/rho) b_{m+1} + b_{m+2}
    #pragma unroll 1
    for (int m = M - 1; m >= 1; --m) {
        tb[lane] = b1;                       // ds_write_b32, conflict-free
        float t  = matvec_row(row, tb);      // (2A/rho) b1
        float bn = fmaf(jc + jc, xv, t + b2);
        b2 = b1; b1 = bn;
        float jm = fmaf((2.f * (float)m) * inv_rho, jc, -jp);
        jp = jc; jc = jm;
        int mm = m - 1;
        if ((mm & 1) == 0) N += (mm > 0) ? (jm + jm) : jm;
    }
    // jc = J~_0 (already folded into N). Final: b0 = J~_0 x + (2A/rho)b1 + b2;
    // result = (b0 - (A/rho) b1) / N  -- reuse t = (2A/rho) b1. (verified R2/R3)
    {
        tb[lane] = b1;
        float t  = matvec_row(row, tb);
        float b0 = fmaf(jc, xv, t + b2);
        float y  = (b0 - 0.5f * t) / N;
        out[bs * 64 + lane] = y;
    }
}

extern "C" void kernel_launch(void* const* d_in, const int* in_sizes, int n_in,
                              void* d_out, int out_size, void* d_ws, size_t ws_size,
                              hipStream_t stream) {
    const float* x = (const float*)d_in[0];
    const float* r = (const float*)d_in[1];
    const float* L = (const float*)d_in[2];
    // d_in[3] = P_sp: identity (allow_mixing=False) -> R_eff = R_r.
    float* out = (float*)d_out;

    int n_tokens = in_sizes[0] / 64;  // B*S = 8192
    int grid = (n_tokens + TOKENS_PER_BLOCK - 1) / TOKENS_PER_BLOCK;
    liepe_kernel<<<grid, TPB, 0, stream>>>(x, r, L, out, n_tokens);
}

// Round 5
// 178.049 us; speedup vs baseline: 2.3833x; 1.4337x over previous
//
#include <hip/hip_runtime.h>

// ExplicitLiePE: y[b,s] = expm(A) @ x[b,s],  A = sum_k r[b,s,k] * 0.5*(L_k - L_k^T)
// (P_sp = identity in this config).
//
// One wave per token; lane i holds row i of 2*A/rho in 64 VGPRs.
// exp(A)x via Jacobi-Anger/Chebyshev + Clenshaw; Bessel coefficients by Miller
// backward recurrence fused into the Clenshaw loop (math verified R2/R3/R4).
//
// R5 vs R4: the matvec is INLINED — R3/R4 passed row[64] by reference into a
// helper, which takes the array's address and demoted it to scratch
// (hbm_bytes 0.8-1.1 GB, VALUBusy <1%). All row[] accesses now have
// compile-time-constant indices in fully-unrolled loops, and tbuf is indexed
// directly (no escaped pointer). No min-waves launch bound (R3's cap provoked
// the allocator; R1/R2 promoted cleanly without one).
// t-broadcast stays on the LDS pipe: 1 ds_write_b32 + 16 same-address
// ds_read_b128 (broadcast, conflict-free) instead of 64 v_readlane on VALU.

#define TPB 256
#define TOKENS_PER_BLOCK 4
#define LPAD 68                  // float stride: rows 16B-aligned for b128 LDS reads
                                 // (R1 measured 0 conflicts); col reads lane-consecutive.
#define LSTRIDE (64 * LPAD)

__global__ __launch_bounds__(TPB) void liepe_kernel(
    const float* __restrict__ x,
    const float* __restrict__ r_grid,
    const float* __restrict__ L_param,
    float* __restrict__ out,
    int n_tokens)
{
    __shared__ __align__(16) float Lsh[3 * LSTRIDE];
    __shared__ __align__(16) float tbuf[TOKENS_PER_BLOCK][64];

    // Stage raw L (3x64x64) into LDS, padded stride. Coalesced global reads.
    for (int idx = threadIdx.x; idx < 3 * 64 * 64; idx += TPB) {
        int k = idx >> 12;
        int rem = idx & 4095;
        int i = rem >> 6;
        int j = rem & 63;
        Lsh[k * LSTRIDE + i * LPAD + j] = L_param[idx];
    }
    __syncthreads();

    const int lane = threadIdx.x & 63;
    const int wid  = threadIdx.x >> 6;
    const int bs   = blockIdx.x * TOKENS_PER_BLOCK + wid;
    if (bs >= n_tokens) return;

    const float r0 = r_grid[bs * 3 + 0];
    const float r1 = r_grid[bs * 3 + 1];
    const float r2 = r_grid[bs * 3 + 2];

    const float sig2 = 0.5f * (r0 * r0 + r1 * r1 + r2 * r2);
    const float rho  = fmaf(16.4f, __builtin_sqrtf(sig2), 1.5f);
    const float inv_rho = 1.0f / rho;
    const int M = (int)rho + 12;

    // rows hold 2*A/rho: coefficient per generator = r_k / rho
    const float c0 = r0 * inv_rho;
    const float c1 = r1 * inv_rho;
    const float c2 = r2 * inv_rho;

    // Build row[j] = (2A/rho)[lane][j] = sum_k c_k * (L_k[lane][j] - L_k[j][lane])
    float row[64];
    #pragma unroll
    for (int j4 = 0; j4 < 64; j4 += 4) {
        float acc0 = 0.f, acc1 = 0.f, acc2 = 0.f, acc3 = 0.f;
        #pragma unroll
        for (int k = 0; k < 3; ++k) {
            const float ck = (k == 0) ? c0 : ((k == 1) ? c1 : c2);
            const float* base = &Lsh[k * LSTRIDE];
            float4 a = *(const float4*)(base + lane * LPAD + j4);
            float b0v = base[(j4 + 0) * LPAD + lane];
            float b1v = base[(j4 + 1) * LPAD + lane];
            float b2v = base[(j4 + 2) * LPAD + lane];
            float b3v = base[(j4 + 3) * LPAD + lane];
            acc0 = fmaf(ck, a.x - b0v, acc0);
            acc1 = fmaf(ck, a.y - b1v, acc1);
            acc2 = fmaf(ck, a.z - b2v, acc2);
            acc3 = fmaf(ck, a.w - b3v, acc3);
        }
        row[j4 + 0] = acc0;
        row[j4 + 1] = acc1;
        row[j4 + 2] = acc2;
        row[j4 + 3] = acc3;
    }

    const float xv = x[bs * 64 + lane];

    // ---- Miller backward recurrence for unnormalized Jm(rho), fused Clenshaw ----
    float jp = 0.f;          // J~_{m+1}
    float jc = 1e-12f;       // J~_{m}, starting at m = ms
    const int ms = M + 10;
    float N = ((ms & 1) == 0) ? (jc + jc) : 0.f;   // normalizer: J0 + 2*sum_even Jm

    for (int m = ms; m > M; --m) {
        float jm = fmaf((2.f * (float)m) * inv_rho, jc, -jp);  // J~_{m-1}
        jp = jc; jc = jm;
        int mm = m - 1;
        if ((mm & 1) == 0) N += (mm > 0) ? (jm + jm) : jm;
    }
    // jc = J~_M.  b_M = a_M * x = 2*J~_M * x
    float b1 = (jc + jc) * xv;
    float b2 = 0.f;
    {   // advance to J~_{M-1}
        float jm = fmaf((2.f * (float)M) * inv_rho, jc, -jp);
        jp = jc; jc = jm;
        int mm = M - 1;
        if ((mm & 1) == 0) N += (mm > 0) ? (jm + jm) : jm;
    }

    // Clenshaw: b_m = 2*J~_m * x + (2A/rho) b_{m+1} + b_{m+2}
    #pragma unroll 1
    for (int m = M - 1; m >= 0; --m) {
        tbuf[wid][lane] = b1;                    // ds_write_b32, conflict-free
        float a0 = 0.f, a1 = 0.f, a2 = 0.f, a3 = 0.f;
        #pragma unroll
        for (int j4 = 0; j4 < 16; ++j4) {
            float4 t4 = *(const float4*)(&tbuf[wid][4 * j4]);  // broadcast read
            a0 = fmaf(row[4 * j4 + 0], t4.x, a0);
            a1 = fmaf(row[4 * j4 + 1], t4.y, a1);
            a2 = fmaf(row[4 * j4 + 2], t4.z, a2);
            a3 = fmaf(row[4 * j4 + 3], t4.w, a3);
        }
        float t = (a0 + a1) + (a2 + a3);         // (2A/rho) b1
        if (m > 0) {
            float bn = fmaf(jc + jc, xv, t + b2);
            b2 = b1; b1 = bn;
            float jm = fmaf((2.f * (float)m) * inv_rho, jc, -jp);
            jp = jc; jc = jm;
            int mm = m - 1;
            if ((mm & 1) == 0) N += (mm > 0) ? (jm + jm) : jm;
        } else {
            // jc = J~_0 (already folded into N).
            // b0 = J~_0 x + (2A/rho) b1 + b2; result = (b0 - (A/rho) b1) / N.
            float b0 = fmaf(jc, xv, t + b2);
            float y  = (b0 - 0.5f * t) / N;
            out[bs * 64 + lane] = y;
        }
    }
}

extern "C" void kernel_launch(void* const* d_in, const int* in_sizes, int n_in,
                              void* d_out, int out_size, void* d_ws, size_t ws_size,
                              hipStream_t stream) {
    const float* x = (const float*)d_in[0];
    const float* r = (const float*)d_in[1];
    const float* L = (const float*)d_in[2];
    // d_in[3] = P_sp: identity (allow_mixing=False) -> R_eff = R_r.
    float* out = (float*)d_out;

    int n_tokens = in_sizes[0] / 64;  // B*S = 8192
    int grid = (n_tokens + TOKENS_PER_BLOCK - 1) / TOKENS_PER_BLOCK;
    liepe_kernel<<<grid, TPB, 0, stream>>>(x, r, L, out, n_tokens);
}